// Round 7
// baseline (1707.488 us; speedup 1.0000x reference)
//
#include <hip/hip_runtime.h>
#include <hip/hip_bf16.h>
#include <math.h>

typedef __attribute__((ext_vector_type(8))) short short8;
typedef __attribute__((ext_vector_type(4))) float f32x4;
typedef __attribute__((ext_vector_type(4))) unsigned u32x4;
typedef unsigned short u16;

__device__ __forceinline__ u16 f2bf(float f) {
    union { float f; unsigned u; } v; v.f = f;
    unsigned r = v.u + 0x7fffu + ((v.u >> 16) & 1u);   // RNE
    return (u16)(r >> 16);
}
__device__ __forceinline__ float bf2f(u16 b) {
    union { unsigned u; float f; } v; v.u = ((unsigned)b) << 16;
    return v.f;
}
__device__ __forceinline__ float fast_sigmoid(float x) {
    return __builtin_amdgcn_rcpf(1.f + __expf(-x));
}
__device__ __forceinline__ float fast_tanh(float x) {
    return 1.f - 2.f * __builtin_amdgcn_rcpf(1.f + __expf(2.f * x));
}
// cached (L1/L2) pipelined 16-B load; asm so it can't be hoisted above spins.
__device__ __forceinline__ u32x4 ldg16(const void* p) {
    u32x4 r;
    asm volatile("global_load_dwordx4 %0, %1, off"
                 : "=v"(r) : "v"(p) : "memory");
    return r;
}
// write-through 16-B store (visible at LLC; consumers plain-load fresh lines)
__device__ __forceinline__ void stg16sc(void* p, u32x4 v) {
    asm volatile("global_store_dwordx4 %0, %1, off sc0 sc1"
                 :: "v"(p), "v"(v) : "memory");
}

// ---------------- consolidated prep kernel ----------------
__device__ __forceinline__ void tr_tile(const float* __restrict__ W,
                                        u16* __restrict__ WT, int K, int N,
                                        int bid, int tid, float (*tile)[33]) {
    int gx = N >> 5;
    int bx = bid % gx, by = bid / gx;
    int n0 = bx * 32, k0 = by * 32;
    int tx = tid & 31, ty = tid >> 5;
    #pragma unroll
    for (int j = 0; j < 32; j += 8)
        tile[ty + j][tx] = W[(size_t)(k0 + ty + j) * N + n0 + tx];
    __syncthreads();
    #pragma unroll
    for (int j = 0; j < 32; j += 8)
        WT[(size_t)(n0 + ty + j) * K + k0 + tx] = f2bf(tile[tx][ty + j]);
}

__global__ __launch_bounds__(256) void k_prep(
    const float* __restrict__ x, u16* __restrict__ Xb,
    const float* __restrict__ h0, u16* __restrict__ hs0, u16* __restrict__ hs1,
    unsigned* __restrict__ ctr,
    const float* __restrict__ Wpre, u16* __restrict__ WTpre,
    const float* __restrict__ Wi0, u16* __restrict__ WTi0,
    const float* __restrict__ Wh0, u16* __restrict__ WTh0,
    const float* __restrict__ Wi1, u16* __restrict__ WTi1,
    const float* __restrict__ Wh1, u16* __restrict__ WTh1,
    const float* __restrict__ Wpost, u16* __restrict__ WTpost,
    const float* __restrict__ Wout, u16* __restrict__ WTout) {
    __shared__ float tile[32][33];
    int bid = blockIdx.x, tid = threadIdx.x;
    if (bid == 0) {                       // zero counters + grid-barrier slots
        for (int i = tid; i < 8192; i += 256) ctr[i] = 0u;
        return;
    }
    bid -= 1;
    if (bid < 16384) {                                   // x -> bf16
        int i = bid * 256 + tid;
        Xb[i] = f2bf(x[i]);
        return;
    }
    bid -= 16384;
    if (bid < 512) {                                     // h0 -> hs slot-0 layout
        int i = bid * 256 + tid;                         // 131072 threads
        int layer = i >> 16, j = i & 65535;
        int b = j >> 10, jj = j & 1023;
        u16 v = f2bf(h0[(size_t)layer * 65536 + j]);
        u16* dst = layer ? hs1 : hs0;
        dst[(size_t)(jj >> 3) * 512 + b * 8 + (jj & 7)] = v;
        return;
    }
    bid -= 512;
    if (bid < 512)  { tr_tile(Wpre,  WTpre,  512,  1024, bid, tid, tile); return; }
    bid -= 512;
    if (bid < 4096) { tr_tile(Wi0,   WTi0,   1024, 4096, bid, tid, tile); return; }
    bid -= 4096;
    if (bid < 4096) { tr_tile(Wh0,   WTh0,   1024, 4096, bid, tid, tile); return; }
    bid -= 4096;
    if (bid < 4096) { tr_tile(Wi1,   WTi1,   1024, 4096, bid, tid, tile); return; }
    bid -= 4096;
    if (bid < 4096) { tr_tile(Wh1,   WTh1,   1024, 4096, bid, tid, tile); return; }
    bid -= 4096;
    if (bid < 1024) { tr_tile(Wpost, WTpost, 1024, 1024, bid, tid, tile); return; }
    bid -= 1024;
    tr_tile(Wout, WTout, 1024, 32, bid, tid, tile);      // 32 tiles
}
#define PREP_BLOCKS (1 + 16384 + 512 + 512 + 4 * 4096 + 1024 + 32)

// ============ fully fused cooperative kernel: pre+LN | scan | post+logits ======
// 256 blocks x 512 threads, 1 block/CU, three phases with counter grid barriers.
// Phase 0: block bk owns rows [bk*32, bk*32+32) of X@Wpre (2 passes x 16 rows):
//   GEMM into LDS f32 tile (whs reuse) -> LN locally (rows block-local; no
//   global f32 round-trip) -> relu -> pack to preS scan layout via sc0/sc1.
// Phase 1: the round-5 known-good scan (669us): leader-poll + LDS gflag relay,
//   64B-stride counters, plain per-block publish, per-wave-group waits, simple
//   2-chain accumulators. Hp stores now sc0/sc1 (consumed intra-kernel).
// Phase 2: block owns rows [bk*32, +32) of Hplain@Wpost (2 passes): GEMM +
//   bias + relu -> bf16 in LDS -> logits (x WTout) straight from LDS -> out.
// Transport rule (rounds 1/3/4 lessons): producers sc0/sc1 write-through,
// consumers PLAIN cached loads (first-touch lines -> LLC-fresh, L2-dedup'd);
// publish = plain store to a private 64B-spaced line; polls leader-only.
#define FBLOCKS 256
__global__ __launch_bounds__(512, 1) void k_fused_all(
    const u16* __restrict__ Xb, const u16* __restrict__ WTpre,
    const float* __restrict__ b_pre, const float* __restrict__ ln_s,
    const float* __restrict__ ln_b,
    const u16* __restrict__ WiT0, const u16* __restrict__ WhT0,
    const u16* __restrict__ WiT1, const u16* __restrict__ WhT1,
    u16* __restrict__ preS, const float* __restrict__ b0v,
    const float* __restrict__ b1v, const float* __restrict__ c0_all,
    u16* __restrict__ hs0, u16* __restrict__ hs1, u16* __restrict__ Hp,
    const u16* __restrict__ WTpost, const float* __restrict__ b_post,
    const u16* __restrict__ WTout, const float* __restrict__ b_out,
    float* __restrict__ out, unsigned* __restrict__ ctr) {
    const int bk = blockIdx.x;
    const int role = bk >> 7;
    const int bkl = bk & 127;
    const int tid = threadIdx.x;
    const int w = tid >> 6, l = tid & 63, lm = l & 15, lq = l >> 4;

    __shared__ u16 whs[65536];          // phase0: f32 tile / phase1: weights / phase2: bf16 tile
    __shared__ float zbuf[2 * 64 * 33]; // phase1 z partials; phase0 LN stats
    __shared__ int gflag[2];

    // ================= phase 0: pre-GEMM + LN + relu -> preS =================
    {
        float* zout = (float*)whs;                    // [16][1036] f32
        float* lnstat = zbuf;                         // [16][2]
        for (int p = 0; p < 2; p++) {
            int R0 = bk * 32 + p * 16;
            #pragma unroll
            for (int ct = 0; ct < 2; ct++) {
                int c0 = w * 128 + ct * 64;
                const u16* arow = Xb + (size_t)(R0 + lm) * 512 + lq * 8;
                const u16* bp0 = WTpre + (size_t)(c0 + lm) * 512 + lq * 8;
                const u16* bp1 = bp0 + 16 * 512;
                const u16* bp2 = bp0 + 32 * 512;
                const u16* bp3 = bp0 + 48 * 512;
                f32x4 a0 = {0.f, 0.f, 0.f, 0.f}, a1 = a0, a2 = a0, a3 = a0;
                for (int k0 = 0; k0 < 512; k0 += 32) {
                    short8 a = *(const short8*)(arow + k0);
                    a0 = __builtin_amdgcn_mfma_f32_16x16x32_bf16(a, *(const short8*)(bp0 + k0), a0, 0, 0, 0);
                    a1 = __builtin_amdgcn_mfma_f32_16x16x32_bf16(a, *(const short8*)(bp1 + k0), a1, 0, 0, 0);
                    a2 = __builtin_amdgcn_mfma_f32_16x16x32_bf16(a, *(const short8*)(bp2 + k0), a2, 0, 0, 0);
                    a3 = __builtin_amdgcn_mfma_f32_16x16x32_bf16(a, *(const short8*)(bp3 + k0), a3, 0, 0, 0);
                }
                f32x4 accs[4] = {a0, a1, a2, a3};
                #pragma unroll
                for (int nt = 0; nt < 4; nt++) {
                    #pragma unroll
                    for (int r = 0; r < 4; r++) {
                        int col = c0 + nt * 16 + lm;
                        zout[(lq * 4 + r) * 1036 + col] = accs[nt][r] + b_pre[col];
                    }
                }
            }
            __syncthreads();
            {   // LN stats: 32 threads per row
                int row = tid >> 5, tr = tid & 31;
                float s = 0.f, ss = 0.f;
                #pragma unroll
                for (int j = 0; j < 32; j++) {
                    float v = zout[row * 1036 + tr + j * 32];
                    s += v; ss += v * v;
                }
                #pragma unroll
                for (int o = 16; o > 0; o >>= 1) {
                    s += __shfl_down(s, o, 32);
                    ss += __shfl_down(ss, o, 32);
                }
                if (tr == 0) {
                    float mu = s * (1.f / 1024.f);
                    float var = ss * (1.f / 1024.f) - mu * mu;
                    lnstat[row * 2] = mu;
                    lnstat[row * 2 + 1] = rsqrtf(var + 1e-6f);
                }
            }
            __syncthreads();
            {   // normalize + relu + pack to preS[t][g][b][8]
                int row = tid >> 5, tr = tid & 31;
                int R = R0 + row, bb = R >> 7, t = R & 127;
                float mu = lnstat[row * 2], inv = lnstat[row * 2 + 1];
                #pragma unroll
                for (int j = 0; j < 4; j++) {
                    int g = tr + j * 32;
                    union { u16 h[8]; u32x4 v; } pk;
                    #pragma unroll
                    for (int e = 0; e < 8; e++) {
                        int col = g * 8 + e;
                        float v = (zout[row * 1036 + col] - mu) * inv * ln_s[col] + ln_b[col];
                        pk.h[e] = f2bf(fmaxf(v, 0.f));
                    }
                    stg16sc(preS + (size_t)t * 65536 + (size_t)g * 512 + bb * 8, pk.v);
                }
            }
            __syncthreads();
        }
    }
    // ---- grid barrier 0
    __syncthreads();
    if (tid == 0) {
        __hip_atomic_fetch_add(&ctr[4096], 1u, __ATOMIC_ACQ_REL, __HIP_MEMORY_SCOPE_AGENT);
        while (__hip_atomic_load(&ctr[4096], __ATOMIC_ACQUIRE, __HIP_MEMORY_SCOPE_AGENT) < (unsigned)FBLOCKS)
            __builtin_amdgcn_s_sleep(2);
    }
    __syncthreads();

    // ================= phase 1: persistent 2-layer LSTM scan =================
    {
        const int kp = w >> 2, rt = w & 3;
        // stage Wi|Wh slices in fragment order (dst = whs + f*8)
        {
            const u16* Wx = role ? WiT1 : WiT0;
            const u16* Wh = role ? WhT1 : WhT0;
            for (int f = tid; f < 8192; f += 512) {
                int flm = f & 15, flq = (f >> 4) & 3;
                int fi = (f >> 6) & 31;
                int rest = f >> 11;
                int fg = rest & 1, fkp = (rest >> 1) & 1;
                int lc = fg * 16 + flm;
                int gcolw = (lc >> 3) * 1024 + bkl * 8 + (lc & 7);
                int k = fi * 32 + flq * 8;
                const u16* src = (fkp == 0 ? Wx : Wh) + (size_t)gcolw * 1024 + k;
                *(short8*)(whs + (size_t)f * 8) = *(const short8*)src;
            }
        }
        if (tid == 0) { gflag[0] = -1; gflag[1] = -1; }
        const int u = tid & 7, b = tid >> 3;
        const int gcol = bkl * 8 + u;
        float c = (c0_all + (size_t)role * 65536)[(size_t)b * 1024 + gcol];
        const float* bv = role ? b1v : b0v;
        float bi0 = bv[gcol], bi1 = bv[1024 + gcol];
        float bi2 = bv[2048 + gcol], bi3 = bv[3072 + gcol];
        u16* hs_my = role ? hs1 : hs0;
        float* c_out = out + (size_t)role * 65536;
        float* h_out = out + 131072 + (size_t)role * 65536;
        const int lanoff = (lq * 16 + lm) * 8;
        __syncthreads();

        for (int t = 0; t < 128; t++) {
            // per-wave-group wait; leader (rt==0) polls, followers spin on LDS
            if (role || kp == 1) {
                int need = (role && kp == 0) ? t + 1 : t;
                if (rt == 0) {
                    if (need > 0) {
                        int cbase = (role && kp) ? 128 : 0;
                        for (;;) {
                            unsigned a0 = __hip_atomic_load(&ctr[(cbase + l) * 16], __ATOMIC_RELAXED,
                                                            __HIP_MEMORY_SCOPE_AGENT);
                            unsigned a1 = __hip_atomic_load(&ctr[(cbase + 64 + l) * 16], __ATOMIC_RELAXED,
                                                            __HIP_MEMORY_SCOPE_AGENT);
                            if (__all((a0 >= (unsigned)need) && (a1 >= (unsigned)need))) break;
                            __builtin_amdgcn_s_sleep(1);
                        }
                    }
                    __hip_atomic_store(&gflag[kp], need, __ATOMIC_RELAXED,
                                       __HIP_MEMORY_SCOPE_WORKGROUP);
                } else {
                    while (__hip_atomic_load(&gflag[kp], __ATOMIC_RELAXED,
                                             __HIP_MEMORY_SCOPE_WORKGROUP) < need)
                        __builtin_amdgcn_s_sleep(1);
                }
            }

            const u16* abase;
            if (!role) abase = (kp == 0) ? preS + (size_t)t * 65536
                                         : hs0 + (size_t)t * 65536;
            else       abase = (kp == 0) ? hs0 + (size_t)(t + 1) * 65536
                                         : hs1 + (size_t)t * 65536;
            const u16* arow = abase + (size_t)lq * 512 + (rt * 16 + lm) * 8;
            const u16* bw0 = whs + kp * 32768 + lanoff;

            f32x4 acc0 = {0.f, 0.f, 0.f, 0.f}, acc1 = acc0;
            #define STEPF(Ai, i)                                                      \
            {   union { u32x4 q; short8 v; } _a; _a.q = (Ai);                         \
                short8 _b0 = *(const short8*)(bw0 + (i) * 512);                       \
                short8 _b1 = *(const short8*)(bw0 + 16384 + (i) * 512);               \
                acc0 = __builtin_amdgcn_mfma_f32_16x16x32_bf16(_a.v, _b0, acc0, 0, 0, 0); \
                acc1 = __builtin_amdgcn_mfma_f32_16x16x32_bf16(_a.v, _b1, acc1, 0, 0, 0); }

            u32x4 A0 = ldg16(arow +     0), A1 = ldg16(arow +  2048);
            u32x4 A2 = ldg16(arow +  4096), A3 = ldg16(arow +  6144);
            u32x4 A4 = ldg16(arow +  8192), A5 = ldg16(arow + 10240);
            u32x4 A6 = ldg16(arow + 12288), A7 = ldg16(arow + 14336);
            u32x4 A8 = ldg16(arow + 16384), A9 = ldg16(arow + 18432);
            u32x4 A10 = ldg16(arow + 20480), A11 = ldg16(arow + 22528);
            u32x4 A12 = ldg16(arow + 24576), A13 = ldg16(arow + 26624);
            u32x4 A14 = ldg16(arow + 28672), A15 = ldg16(arow + 30720);
            u32x4 A16 = ldg16(arow + 32768), A17 = ldg16(arow + 34816);
            u32x4 A18 = ldg16(arow + 36864), A19 = ldg16(arow + 38912);
            u32x4 A20 = ldg16(arow + 40960), A21 = ldg16(arow + 43008);
            u32x4 A22 = ldg16(arow + 45056), A23 = ldg16(arow + 47104);
            u32x4 A24 = ldg16(arow + 49152), A25 = ldg16(arow + 51200);
            u32x4 A26 = ldg16(arow + 53248), A27 = ldg16(arow + 55296);
            u32x4 A28 = ldg16(arow + 57344), A29 = ldg16(arow + 59392);
            u32x4 A30 = ldg16(arow + 61440), A31 = ldg16(arow + 63488);
            asm volatile("s_waitcnt vmcnt(24)"
                         : "+v"(A0), "+v"(A1), "+v"(A2), "+v"(A3),
                           "+v"(A4), "+v"(A5), "+v"(A6), "+v"(A7) :: "memory");
            STEPF(A0, 0) STEPF(A1, 1) STEPF(A2, 2) STEPF(A3, 3)
            STEPF(A4, 4) STEPF(A5, 5) STEPF(A6, 6) STEPF(A7, 7)
            asm volatile("s_waitcnt vmcnt(16)"
                         : "+v"(A8), "+v"(A9), "+v"(A10), "+v"(A11),
                           "+v"(A12), "+v"(A13), "+v"(A14), "+v"(A15) :: "memory");
            STEPF(A8, 8) STEPF(A9, 9) STEPF(A10, 10) STEPF(A11, 11)
            STEPF(A12, 12) STEPF(A13, 13) STEPF(A14, 14) STEPF(A15, 15)
            asm volatile("s_waitcnt vmcnt(8)"
                         : "+v"(A16), "+v"(A17), "+v"(A18), "+v"(A19),
                           "+v"(A20), "+v"(A21), "+v"(A22), "+v"(A23) :: "memory");
            STEPF(A16, 16) STEPF(A17, 17) STEPF(A18, 18) STEPF(A19, 19)
            STEPF(A20, 20) STEPF(A21, 21) STEPF(A22, 22) STEPF(A23, 23)
            asm volatile("s_waitcnt vmcnt(0)"
                         : "+v"(A24), "+v"(A25), "+v"(A26), "+v"(A27),
                           "+v"(A28), "+v"(A29), "+v"(A30), "+v"(A31) :: "memory");
            STEPF(A24, 24) STEPF(A25, 25) STEPF(A26, 26) STEPF(A27, 27)
            STEPF(A28, 28) STEPF(A29, 29) STEPF(A30, 30) STEPF(A31, 31)
            #undef STEPF

            {
                float* zb = zbuf + (size_t)kp * 2112;
                #pragma unroll
                for (int r = 0; r < 4; r++) {
                    int row = rt * 16 + lq * 4 + r;
                    zb[row * 33 + lm] = acc0[r];
                    zb[row * 33 + 16 + lm] = acc1[r];
                }
            }
            __syncthreads();   // (1) zbuf complete

            {
                const float* z0 = zbuf + (size_t)b * 33;
                const float* z1 = z0 + 2112;
                float gi = z0[u]      + z1[u]      + bi0;
                float gf = z0[8 + u]  + z1[8 + u]  + bi1;
                float gg = z0[16 + u] + z1[16 + u] + bi2;
                float go = z0[24 + u] + z1[24 + u] + bi3;
                gi = fast_sigmoid(gi);
                gf = fast_sigmoid(gf);
                gg = fast_tanh(gg);
                go = fast_sigmoid(go);
                c = gf * c + gi * gg;
                float h = go * fast_tanh(c);
                unsigned hv = (unsigned)f2bf(h);
                int base = l & 56;
                unsigned p0 = __shfl(hv, base + 0, 64) | (__shfl(hv, base + 1, 64) << 16);
                unsigned p1 = __shfl(hv, base + 2, 64) | (__shfl(hv, base + 3, 64) << 16);
                unsigned p2 = __shfl(hv, base + 4, 64) | (__shfl(hv, base + 5, 64) << 16);
                unsigned p3 = __shfl(hv, base + 6, 64) | (__shfl(hv, base + 7, 64) << 16);
                if (u == 0) {
                    u32x4 pv = {p0, p1, p2, p3};
                    stg16sc(hs_my + (size_t)(t + 1) * 65536 + (size_t)bkl * 512 + b * 8, pv);
                    if (role)   // consumed intra-kernel by phase 2 -> write-through
                        stg16sc(Hp + (size_t)(t * 64 + b) * 1024 + bkl * 8, pv);
                }
                if (t == 127) {
                    c_out[(size_t)b * 1024 + gcol] = c;
                    h_out[(size_t)b * 1024 + gcol] = h;
                }
            }
            __syncthreads();   // (2) zbuf consumed + store drain

            if (tid == 0)
                __hip_atomic_store(&ctr[bk * 16], (unsigned)(t + 1), __ATOMIC_RELAXED,
                                   __HIP_MEMORY_SCOPE_AGENT);
        }
    }
    // ---- grid barrier 1
    __syncthreads();
    if (tid == 0) {
        __hip_atomic_fetch_add(&ctr[4160], 1u, __ATOMIC_ACQ_REL, __HIP_MEMORY_SCOPE_AGENT);
        while (__hip_atomic_load(&ctr[4160], __ATOMIC_ACQUIRE, __HIP_MEMORY_SCOPE_AGENT) < (unsigned)FBLOCKS)
            __builtin_amdgcn_s_sleep(2);
    }
    __syncthreads();

    // ================= phase 2: post-GEMM + relu + logits =================
    {
        u16* pact = whs;                               // [16][1040] bf16
        for (int p = 0; p < 2; p++) {
            int R0 = bk * 32 + p * 16;                 // Hplain row base (t*64+b)
            #pragma unroll
            for (int ct = 0; ct < 2; ct++) {
                int c0 = w * 128 + ct * 64;
                const u16* arow = Hp + (size_t)(R0 + lm) * 1024 + lq * 8;
                const u16* bp0 = WTpost + (size_t)(c0 + lm) * 1024 + lq * 8;
                const u16* bp1 = bp0 + 16 * 1024;
                const u16* bp2 = bp0 + 32 * 1024;
                const u16* bp3 = bp0 + 48 * 1024;
                f32x4 a0 = {0.f, 0.f, 0.f, 0.f}, a1 = a0, a2 = a0, a3 = a0;
                for (int k0 = 0; k0 < 1024; k0 += 32) {
                    short8 a = *(const short8*)(arow + k0);
                    a0 = __builtin_amdgcn_mfma_f32_16x16x32_bf16(a, *(const short8*)(bp0 + k0), a0, 0, 0, 0);
                    a1 = __builtin_amdgcn_mfma_f32_16x16x32_bf16(a, *(const short8*)(bp1 + k0), a1, 0, 0, 0);
                    a2 = __builtin_amdgcn_mfma_f32_16x16x32_bf16(a, *(const short8*)(bp2 + k0), a2, 0, 0, 0);
                    a3 = __builtin_amdgcn_mfma_f32_16x16x32_bf16(a, *(const short8*)(bp3 + k0), a3, 0, 0, 0);
                }
                f32x4 accs[4] = {a0, a1, a2, a3};
                #pragma unroll
                for (int nt = 0; nt < 4; nt++) {
                    #pragma unroll
                    for (int r = 0; r < 4; r++) {
                        int col = c0 + nt * 16 + lm;
                        float v = accs[nt][r] + b_post[col];
                        pact[(lq * 4 + r) * 1040 + col] = f2bf(fmaxf(v, 0.f));
                    }
                }
            }
            __syncthreads();
            {   // logits from LDS: thread (row, n)
                int row = tid >> 5, n = tid & 31;
                const u16* av = pact + row * 1040;
                const u16* wv = WTout + (size_t)n * 1024;
                float s = 0.f;
                for (int k = 0; k < 1024; k += 8) {
                    short8 a8 = *(const short8*)(av + k);
                    short8 w8 = *(const short8*)(wv + k);
                    #pragma unroll
                    for (int jj = 0; jj < 8; jj++)
                        s += bf2f((u16)a8[jj]) * bf2f((u16)w8[jj]);
                }
                int R = R0 + row, t = R >> 6, bb = R & 63;
                out[262144 + ((size_t)bb * 128 + t) * 32 + n] = s + b_out[n];
            }
            __syncthreads();
        }
    }
}

// ---------------- launcher ----------------
extern "C" void kernel_launch(void* const* d_in, const int* in_sizes, int n_in,
                              void* d_out, int out_size, void* d_ws, size_t ws_size,
                              hipStream_t stream) {
    const float* x      = (const float*)d_in[0];
    const float* c0     = (const float*)d_in[1];
    const float* h0     = (const float*)d_in[2];
    const float* W_pre  = (const float*)d_in[3];
    const float* b_pre  = (const float*)d_in[4];
    const float* ln_s   = (const float*)d_in[5];
    const float* ln_b   = (const float*)d_in[6];
    const float* Wi0    = (const float*)d_in[7];
    const float* Wh0    = (const float*)d_in[8];
    const float* b0     = (const float*)d_in[9];
    const float* Wi1    = (const float*)d_in[10];
    const float* Wh1    = (const float*)d_in[11];
    const float* b1     = (const float*)d_in[12];
    const float* W_post = (const float*)d_in[13];
    const float* b_post = (const float*)d_in[14];
    const float* W_out  = (const float*)d_in[15];
    const float* b_out  = (const float*)d_in[16];
    float* out = (float*)d_out;

    char* ws = (char*)d_ws;
    size_t off = 0;
    auto alloc = [&](size_t bytes) {
        void* p = ws + off;
        off += (bytes + 255) & ~(size_t)255;
        return p;
    };
    u16* WTpre  = (u16*)alloc((size_t)1024 * 512 * 2);
    u16* WTi0   = (u16*)alloc((size_t)4096 * 1024 * 2);
    u16* WTh0   = (u16*)alloc((size_t)4096 * 1024 * 2);
    u16* WTi1   = (u16*)alloc((size_t)4096 * 1024 * 2);
    u16* WTh1   = (u16*)alloc((size_t)4096 * 1024 * 2);
    u16* WTpost = (u16*)alloc((size_t)1024 * 1024 * 2);
    u16* WTout  = (u16*)alloc((size_t)32 * 1024 * 2);
    u16* Xb     = (u16*)alloc((size_t)8192 * 512 * 2);
    u16* preS   = (u16*)alloc((size_t)128 * 65536 * 2);   // preact, scan layout
    u16* hs0    = (u16*)alloc((size_t)129 * 65536 * 2);
    u16* hs1    = (u16*)alloc((size_t)129 * 65536 * 2);
    unsigned* ctr = (unsigned*)alloc(32768);
    u16* Hplain = (u16*)alloc((size_t)8192 * 1024 * 2);

    // prep: ctr/barrier zero + x/h0 conversions + all weight transposes
    k_prep<<<PREP_BLOCKS, 256, 0, stream>>>(
        x, Xb, h0, hs0, hs1, ctr,
        W_pre, WTpre, Wi0, WTi0, Wh0, WTh0, Wi1, WTi1, Wh1, WTh1,
        W_post, WTpost, W_out, WTout);

    // fused: pre-GEMM+LN | 2-layer scan | post-GEMM+logits
    {
        const u16* Xb_ = Xb; const u16* WTpre_ = WTpre;
        const float* bpre_ = b_pre; const float* lns_ = ln_s; const float* lnb_ = ln_b;
        const u16* WiT0_ = WTi0; const u16* WhT0_ = WTh0;
        const u16* WiT1_ = WTi1; const u16* WhT1_ = WTh1;
        u16* preS_ = preS; const float* b0_ = b0; const float* b1_ = b1;
        const float* c0_ = c0; u16* hs0_ = hs0; u16* hs1_ = hs1; u16* Hp_ = Hplain;
        const u16* WTpost_ = WTpost; const float* bpost_ = b_post;
        const u16* WTout_ = WTout; const float* bout_ = b_out;
        float* out_ = out; unsigned* ctr_ = ctr;
        void* args[] = {&Xb_, &WTpre_, &bpre_, &lns_, &lnb_,
                        &WiT0_, &WhT0_, &WiT1_, &WhT1_,
                        &preS_, &b0_, &b1_, &c0_, &hs0_, &hs1_, &Hp_,
                        &WTpost_, &bpost_, &WTout_, &bout_, &out_, &ctr_};
        hipLaunchCooperativeKernel((void*)k_fused_all, dim3(FBLOCKS), dim3(512),
                                   args, 0, stream);
    }
}

// Round 8
// 1057.589 us; speedup vs baseline: 1.6145x; 1.6145x over previous
//
#include <hip/hip_runtime.h>
#include <hip/hip_bf16.h>
#include <math.h>

typedef __attribute__((ext_vector_type(8))) short short8;
typedef __attribute__((ext_vector_type(4))) float f32x4;
typedef __attribute__((ext_vector_type(4))) unsigned u32x4;
typedef unsigned short u16;

__device__ __forceinline__ u16 f2bf(float f) {
    union { float f; unsigned u; } v; v.f = f;
    unsigned r = v.u + 0x7fffu + ((v.u >> 16) & 1u);   // RNE
    return (u16)(r >> 16);
}
__device__ __forceinline__ float bf2f(u16 b) {
    union { unsigned u; float f; } v; v.u = ((unsigned)b) << 16;
    return v.f;
}
__device__ __forceinline__ float fast_sigmoid(float x) {
    return __builtin_amdgcn_rcpf(1.f + __expf(-x));
}
__device__ __forceinline__ float fast_tanh(float x) {
    return 1.f - 2.f * __builtin_amdgcn_rcpf(1.f + __expf(2.f * x));
}
// cached (L1/L2) pipelined 16-B load; asm so it can't be hoisted above spins.
__device__ __forceinline__ u32x4 ldg16(const void* p) {
    u32x4 r;
    asm volatile("global_load_dwordx4 %0, %1, off"
                 : "=v"(r) : "v"(p) : "memory");
    return r;
}

// ---------------- consolidated prep kernel ----------------
__device__ __forceinline__ void tr_tile(const float* __restrict__ W,
                                        u16* __restrict__ WT, int K, int N,
                                        int bid, int tid, float (*tile)[33]) {
    int gx = N >> 5;
    int bx = bid % gx, by = bid / gx;
    int n0 = bx * 32, k0 = by * 32;
    int tx = tid & 31, ty = tid >> 5;
    #pragma unroll
    for (int j = 0; j < 32; j += 8)
        tile[ty + j][tx] = W[(size_t)(k0 + ty + j) * N + n0 + tx];
    __syncthreads();
    #pragma unroll
    for (int j = 0; j < 32; j += 8)
        WT[(size_t)(n0 + ty + j) * K + k0 + tx] = f2bf(tile[tx][ty + j]);
}

__global__ __launch_bounds__(256) void k_prep(
    const float* __restrict__ x, u16* __restrict__ Xb,
    const float* __restrict__ h0, u16* __restrict__ hs0, u16* __restrict__ hs1,
    unsigned* __restrict__ ctr,
    const float* __restrict__ Wpre, u16* __restrict__ WTpre,
    const float* __restrict__ Wi0, u16* __restrict__ WTi0,
    const float* __restrict__ Wh0, u16* __restrict__ WTh0,
    const float* __restrict__ Wi1, u16* __restrict__ WTi1,
    const float* __restrict__ Wh1, u16* __restrict__ WTh1,
    const float* __restrict__ Wpost, u16* __restrict__ WTpost,
    const float* __restrict__ Wout, u16* __restrict__ WTout) {
    __shared__ float tile[32][33];
    int bid = blockIdx.x, tid = threadIdx.x;
    if (bid == 0) {                                      // zero 64B-stride counters
        for (int i = tid; i < 4096; i += 256) ctr[i] = 0u;
        return;
    }
    bid -= 1;
    if (bid < 16384) {                                   // x -> bf16
        int i = bid * 256 + tid;
        Xb[i] = f2bf(x[i]);
        return;
    }
    bid -= 16384;
    if (bid < 512) {                                     // h0 -> hs slot-0 layout
        int i = bid * 256 + tid;                         // 131072 threads
        int layer = i >> 16, j = i & 65535;
        int b = j >> 10, jj = j & 1023;
        u16 v = f2bf(h0[(size_t)layer * 65536 + j]);
        u16* dst = layer ? hs1 : hs0;
        dst[(size_t)(jj >> 3) * 512 + b * 8 + (jj & 7)] = v;
        return;
    }
    bid -= 512;
    if (bid < 512)  { tr_tile(Wpre,  WTpre,  512,  1024, bid, tid, tile); return; }
    bid -= 512;
    if (bid < 4096) { tr_tile(Wi0,   WTi0,   1024, 4096, bid, tid, tile); return; }
    bid -= 4096;
    if (bid < 4096) { tr_tile(Wh0,   WTh0,   1024, 4096, bid, tid, tile); return; }
    bid -= 4096;
    if (bid < 4096) { tr_tile(Wi1,   WTi1,   1024, 4096, bid, tid, tile); return; }
    bid -= 4096;
    if (bid < 4096) { tr_tile(Wh1,   WTh1,   1024, 4096, bid, tid, tile); return; }
    bid -= 4096;
    if (bid < 1024) { tr_tile(Wpost, WTpost, 1024, 1024, bid, tid, tile); return; }
    bid -= 1024;
    tr_tile(Wout, WTout, 1024, 32, bid, tid, tile);      // 32 tiles
}
#define PREP_BLOCKS (1 + 16384 + 512 + 512 + 4 * 4096 + 1024 + 32)

// ---------------- k_pre: Dense(512->1024) + bias + LN + relu -> preS ----------------
// 512 blocks x 512 threads (8 waves). Block owns 16 rows x ALL 1024 cols, so
// LN is block-local (no f32 round-trip). K is a RUNTIME arg: prevents the
// round-7 full-unroll spill blowup. Epilogue math = round-7 phase 0 (verified).
__global__ __launch_bounds__(512) void k_pre(
    const u16* __restrict__ Xb, const u16* __restrict__ WTpre,
    const float* __restrict__ b_pre, const float* __restrict__ ln_s,
    const float* __restrict__ ln_b, u16* __restrict__ preS, int K) {
    __shared__ float zout[16 * 1036];
    __shared__ float lnstat[32];
    const int tid = threadIdx.x;
    const int w = tid >> 6, l = tid & 63, lm = l & 15, lq = l >> 4;
    const int R0 = blockIdx.x * 16;
    const int c0 = w * 128;
    const u16* arow = Xb + (size_t)(R0 + lm) * K + lq * 8;
    const u16* bp = WTpre + (size_t)(c0 + lm) * K + lq * 8;
    f32x4 zv = {0.f, 0.f, 0.f, 0.f};
    f32x4 acc[8] = {zv, zv, zv, zv, zv, zv, zv, zv};
    for (int k0 = 0; k0 < K; k0 += 32) {
        short8 a = *(const short8*)(arow + k0);
        #pragma unroll
        for (int f = 0; f < 8; f++)
            acc[f] = __builtin_amdgcn_mfma_f32_16x16x32_bf16(
                a, *(const short8*)(bp + (size_t)f * 16 * K + k0), acc[f], 0, 0, 0);
    }
    #pragma unroll
    for (int f = 0; f < 8; f++) {
        #pragma unroll
        for (int r = 0; r < 4; r++) {
            int col = c0 + f * 16 + lm;
            zout[(lq * 4 + r) * 1036 + col] = acc[f][r] + b_pre[col];
        }
    }
    __syncthreads();
    {   // LN stats: 32 threads per row
        int row = tid >> 5, tr = tid & 31;
        float s = 0.f, ss = 0.f;
        #pragma unroll
        for (int j = 0; j < 32; j++) {
            float v = zout[row * 1036 + tr + j * 32];
            s += v; ss += v * v;
        }
        #pragma unroll
        for (int o = 16; o > 0; o >>= 1) {
            s += __shfl_down(s, o, 32);
            ss += __shfl_down(ss, o, 32);
        }
        if (tr == 0) {
            float mu = s * (1.f / 1024.f);
            float var = ss * (1.f / 1024.f) - mu * mu;
            lnstat[row * 2] = mu;
            lnstat[row * 2 + 1] = rsqrtf(var + 1e-6f);
        }
    }
    __syncthreads();
    {   // normalize + relu + pack to preS[t][g][b][8]
        int row = tid >> 5, tr = tid & 31;
        int R = R0 + row, bb = R >> 7, t = R & 127;
        float mu = lnstat[row * 2], inv = lnstat[row * 2 + 1];
        #pragma unroll
        for (int j = 0; j < 4; j++) {
            int g = tr + j * 32;
            union { u16 h[8]; u32x4 v; } pk;
            #pragma unroll
            for (int e = 0; e < 8; e++) {
                int col = g * 8 + e;
                float v = (zout[row * 1036 + col] - mu) * inv * ln_s[col] + ln_b[col];
                pk.h[e] = f2bf(fmaxf(v, 0.f));
            }
            *(u32x4*)(preS + (size_t)t * 65536 + (size_t)g * 512 + bb * 8) = pk.v;
        }
    }
}

// ---------------- k_post: Dense(1024->1024) + bias + relu -> LDS -> logits ----------------
// 512 blocks x 512 threads. Block owns 16 Hp rows x ALL 1024 cols; activations
// stay in LDS; logits computed from LDS (no postact round-trip). K runtime.
// Epilogue math = round-7 phase 2 (verified).
__global__ __launch_bounds__(512) void k_post(
    const u16* __restrict__ Hp, const u16* __restrict__ WTpost,
    const float* __restrict__ b_post, const u16* __restrict__ WTout,
    const float* __restrict__ b_out, float* __restrict__ out, int K) {
    __shared__ u16 pact[16 * 1040];
    const int tid = threadIdx.x;
    const int w = tid >> 6, l = tid & 63, lm = l & 15, lq = l >> 4;
    const int R0 = blockIdx.x * 16;                      // Hp row base (t*64+b)
    const int c0 = w * 128;
    const u16* arow = Hp + (size_t)(R0 + lm) * K + lq * 8;
    const u16* bp = WTpost + (size_t)(c0 + lm) * K + lq * 8;
    f32x4 zv = {0.f, 0.f, 0.f, 0.f};
    f32x4 acc[8] = {zv, zv, zv, zv, zv, zv, zv, zv};
    for (int k0 = 0; k0 < K; k0 += 32) {
        short8 a = *(const short8*)(arow + k0);
        #pragma unroll
        for (int f = 0; f < 8; f++)
            acc[f] = __builtin_amdgcn_mfma_f32_16x16x32_bf16(
                a, *(const short8*)(bp + (size_t)f * 16 * K + k0), acc[f], 0, 0, 0);
    }
    #pragma unroll
    for (int f = 0; f < 8; f++) {
        #pragma unroll
        for (int r = 0; r < 4; r++) {
            int col = c0 + f * 16 + lm;
            float v = acc[f][r] + b_post[col];
            pact[(lq * 4 + r) * 1040 + col] = f2bf(fmaxf(v, 0.f));
        }
    }
    __syncthreads();
    {   // logits from LDS: thread (row, n)
        int row = tid >> 5, n = tid & 31;
        const u16* av = pact + row * 1040;
        const u16* wv = WTout + (size_t)n * 1024;
        float s = 0.f;
        for (int k = 0; k < 1024; k += 8) {
            short8 a8 = *(const short8*)(av + k);
            short8 w8 = *(const short8*)(wv + k);
            #pragma unroll
            for (int jj = 0; jj < 8; jj++)
                s += bf2f((u16)a8[jj]) * bf2f((u16)w8[jj]);
        }
        int R = R0 + row, t = R >> 6, bb = R & 63;
        out[262144 + ((size_t)bb * 128 + t) * 32 + n] = s + b_out[n];
    }
}

// ---------------- fused symmetric 2-layer persistent LSTM scan ----------------
// ROUND-8: bit-identical to round-5's known-good scan (669us): 64B-stride
// counters, plain per-block publish store, leader-poll (rt==0) + LDS gflag
// relay, per-wave-group waits, 4-way acc split (neutral but harmless).
#define FBLOCKS 256
__global__ __launch_bounds__(512, 1) void k_lstm_fused(
    const u16* __restrict__ WiT0, const u16* __restrict__ WhT0,
    const u16* __restrict__ WiT1, const u16* __restrict__ WhT1,
    const u16* __restrict__ preS, const float* __restrict__ b0v,
    const float* __restrict__ b1v, const float* __restrict__ c0_all,
    u16* __restrict__ hs0, u16* __restrict__ hs1, u16* __restrict__ Hp,
    float* __restrict__ out, unsigned* __restrict__ ctr) {
    const int bk = blockIdx.x;
    const int role = bk >> 7;          // 0: layer0, 1: layer1
    const int bkl = bk & 127;
    const int tid = threadIdx.x;
    const int w = tid >> 6, l = tid & 63, lm = l & 15, lq = l >> 4;
    const int kp = w >> 2, rt = w & 3;

    __shared__ u16 whs[65536];          // 128 KB fragment-ordered [Wi;Wh]
    __shared__ float zbuf[2 * 64 * 33]; // [kp][batch][32 cols]
    __shared__ int gflag[2];            // per-kp-group LDS relay of leader poll

    // ---- stage Wi|Wh slices in fragment order (dst = whs + f*8)
    {
        const u16* Wx = role ? WiT1 : WiT0;
        const u16* Wh = role ? WhT1 : WhT0;
        for (int f = tid; f < 8192; f += 512) {
            int flm = f & 15, flq = (f >> 4) & 3;
            int fi = (f >> 6) & 31;
            int rest = f >> 11;
            int fg = rest & 1, fkp = (rest >> 1) & 1;
            int lc = fg * 16 + flm;
            int gcolw = (lc >> 3) * 1024 + bkl * 8 + (lc & 7);
            int k = fi * 32 + flq * 8;
            const u16* src = (fkp == 0 ? Wx : Wh) + (size_t)gcolw * 1024 + k;
            *(short8*)(whs + (size_t)f * 8) = *(const short8*)src;
        }
    }
    if (tid == 0) { gflag[0] = -1; gflag[1] = -1; }
    const int u = tid & 7, b = tid >> 3;
    const int gcol = bkl * 8 + u;
    float c = (c0_all + (size_t)role * 65536)[(size_t)b * 1024 + gcol];
    const float* bv = role ? b1v : b0v;
    float bi0 = bv[gcol], bi1 = bv[1024 + gcol];
    float bi2 = bv[2048 + gcol], bi3 = bv[3072 + gcol];
    u16* hs_my = role ? hs1 : hs0;
    float* c_out = out + (size_t)role * 65536;
    float* h_out = out + 131072 + (size_t)role * 65536;
    const int lanoff = (lq * 16 + lm) * 8;
    __syncthreads();

    for (int t = 0; t < 128; t++) {
        // ---- per-wave-group dependency wait; leader (rt==0) polls global,
        // followers spin on LDS flag. role-0 kp=0 (static preS) never waits.
        if (role || kp == 1) {
            int need = (role && kp == 0) ? t + 1 : t;
            if (rt == 0) {
                if (need > 0) {
                    int cbase = (role && kp) ? 128 : 0;   // role-0 lines or role-1 lines
                    for (;;) {
                        unsigned a0 = __hip_atomic_load(&ctr[(cbase + l) * 16], __ATOMIC_RELAXED,
                                                        __HIP_MEMORY_SCOPE_AGENT);
                        unsigned a1 = __hip_atomic_load(&ctr[(cbase + 64 + l) * 16], __ATOMIC_RELAXED,
                                                        __HIP_MEMORY_SCOPE_AGENT);
                        if (__all((a0 >= (unsigned)need) && (a1 >= (unsigned)need))) break;
                        __builtin_amdgcn_s_sleep(1);
                    }
                }
                __hip_atomic_store(&gflag[kp], need, __ATOMIC_RELAXED,
                                   __HIP_MEMORY_SCOPE_WORKGROUP);
            } else {
                while (__hip_atomic_load(&gflag[kp], __ATOMIC_RELAXED,
                                         __HIP_MEMORY_SCOPE_WORKGROUP) < need)
                    __builtin_amdgcn_s_sleep(1);
            }
        }

        // ---- A source for this wave's K-half
        const u16* abase;
        if (!role) abase = (kp == 0) ? preS + (size_t)t * 65536
                                     : hs0 + (size_t)t * 65536;
        else       abase = (kp == 0) ? hs0 + (size_t)(t + 1) * 65536
                                     : hs1 + (size_t)t * 65536;
        const u16* arow = abase + (size_t)lq * 512 + (rt * 16 + lm) * 8;
        const u16* bw0 = whs + kp * 32768 + lanoff;

        // 4-way split accumulators: dep-chain depth 8 instead of 32
        f32x4 zv = {0.f, 0.f, 0.f, 0.f};
        f32x4 ac0[4] = {zv, zv, zv, zv}, ac1[4] = {zv, zv, zv, zv};
        #define STEPF(Ai, i)                                                      \
        {   union { u32x4 q; short8 v; } _a; _a.q = (Ai);                         \
            short8 _b0 = *(const short8*)(bw0 + (i) * 512);                       \
            short8 _b1 = *(const short8*)(bw0 + 16384 + (i) * 512);               \
            ac0[(i) & 3] = __builtin_amdgcn_mfma_f32_16x16x32_bf16(_a.v, _b0, ac0[(i) & 3], 0, 0, 0); \
            ac1[(i) & 3] = __builtin_amdgcn_mfma_f32_16x16x32_bf16(_a.v, _b1, ac1[(i) & 3], 0, 0, 0); }

        u32x4 A0 = ldg16(arow +     0), A1 = ldg16(arow +  2048);
        u32x4 A2 = ldg16(arow +  4096), A3 = ldg16(arow +  6144);
        u32x4 A4 = ldg16(arow +  8192), A5 = ldg16(arow + 10240);
        u32x4 A6 = ldg16(arow + 12288), A7 = ldg16(arow + 14336);
        u32x4 A8 = ldg16(arow + 16384), A9 = ldg16(arow + 18432);
        u32x4 A10 = ldg16(arow + 20480), A11 = ldg16(arow + 22528);
        u32x4 A12 = ldg16(arow + 24576), A13 = ldg16(arow + 26624);
        u32x4 A14 = ldg16(arow + 28672), A15 = ldg16(arow + 30720);
        u32x4 A16 = ldg16(arow + 32768), A17 = ldg16(arow + 34816);
        u32x4 A18 = ldg16(arow + 36864), A19 = ldg16(arow + 38912);
        u32x4 A20 = ldg16(arow + 40960), A21 = ldg16(arow + 43008);
        u32x4 A22 = ldg16(arow + 45056), A23 = ldg16(arow + 47104);
        u32x4 A24 = ldg16(arow + 49152), A25 = ldg16(arow + 51200);
        u32x4 A26 = ldg16(arow + 53248), A27 = ldg16(arow + 55296);
        u32x4 A28 = ldg16(arow + 57344), A29 = ldg16(arow + 59392);
        u32x4 A30 = ldg16(arow + 61440), A31 = ldg16(arow + 63488);
        asm volatile("s_waitcnt vmcnt(24)"
                     : "+v"(A0), "+v"(A1), "+v"(A2), "+v"(A3),
                       "+v"(A4), "+v"(A5), "+v"(A6), "+v"(A7) :: "memory");
        STEPF(A0, 0) STEPF(A1, 1) STEPF(A2, 2) STEPF(A3, 3)
        STEPF(A4, 4) STEPF(A5, 5) STEPF(A6, 6) STEPF(A7, 7)
        asm volatile("s_waitcnt vmcnt(16)"
                     : "+v"(A8), "+v"(A9), "+v"(A10), "+v"(A11),
                       "+v"(A12), "+v"(A13), "+v"(A14), "+v"(A15) :: "memory");
        STEPF(A8, 8) STEPF(A9, 9) STEPF(A10, 10) STEPF(A11, 11)
        STEPF(A12, 12) STEPF(A13, 13) STEPF(A14, 14) STEPF(A15, 15)
        asm volatile("s_waitcnt vmcnt(8)"
                     : "+v"(A16), "+v"(A17), "+v"(A18), "+v"(A19),
                       "+v"(A20), "+v"(A21), "+v"(A22), "+v"(A23) :: "memory");
        STEPF(A16, 16) STEPF(A17, 17) STEPF(A18, 18) STEPF(A19, 19)
        STEPF(A20, 20) STEPF(A21, 21) STEPF(A22, 22) STEPF(A23, 23)
        asm volatile("s_waitcnt vmcnt(0)"
                     : "+v"(A24), "+v"(A25), "+v"(A26), "+v"(A27),
                       "+v"(A28), "+v"(A29), "+v"(A30), "+v"(A31) :: "memory");
        STEPF(A24, 24) STEPF(A25, 25) STEPF(A26, 26) STEPF(A27, 27)
        STEPF(A28, 28) STEPF(A29, 29) STEPF(A30, 30) STEPF(A31, 31)
        #undef STEPF
        f32x4 acc0 = (ac0[0] + ac0[1]) + (ac0[2] + ac0[3]);
        f32x4 acc1 = (ac1[0] + ac1[1]) + (ac1[2] + ac1[3]);

        // z-tile -> LDS: row = rt*16 + lq*4 + r ; cols lm (grp0), 16+lm (grp1)
        {
            float* zb = zbuf + (size_t)kp * 2112;
            #pragma unroll
            for (int r = 0; r < 4; r++) {
                int row = rt * 16 + lq * 4 + r;
                zb[row * 33 + lm] = acc0[r];
                zb[row * 33 + 16 + lm] = acc1[r];
            }
        }
        __syncthreads();   // (1) zbuf complete

        // gates: thread (b,u); local col lc = gate*8+u
        {
            const float* z0 = zbuf + (size_t)b * 33;
            const float* z1 = z0 + 2112;
            float gi = z0[u]      + z1[u]      + bi0;
            float gf = z0[8 + u]  + z1[8 + u]  + bi1;
            float gg = z0[16 + u] + z1[16 + u] + bi2;
            float go = z0[24 + u] + z1[24 + u] + bi3;
            gi = fast_sigmoid(gi);
            gf = fast_sigmoid(gf);
            gg = fast_tanh(gg);
            go = fast_sigmoid(go);
            c = gf * c + gi * gg;
            float h = go * fast_tanh(c);
            // pack batch row's 8 bf16 into one dwordx4; lane u==0 stores
            unsigned hv = (unsigned)f2bf(h);
            int base = l & 56;
            unsigned p0 = __shfl(hv, base + 0, 64) | (__shfl(hv, base + 1, 64) << 16);
            unsigned p1 = __shfl(hv, base + 2, 64) | (__shfl(hv, base + 3, 64) << 16);
            unsigned p2 = __shfl(hv, base + 4, 64) | (__shfl(hv, base + 5, 64) << 16);
            unsigned p3 = __shfl(hv, base + 6, 64) | (__shfl(hv, base + 7, 64) << 16);
            if (u == 0) {
                u32x4 pv = {p0, p1, p2, p3};
                u16* dst = hs_my + (size_t)(t + 1) * 65536 + (size_t)bkl * 512 + b * 8;
                asm volatile("global_store_dwordx4 %0, %1, off sc0 sc1"
                             :: "v"(dst), "v"(pv) : "memory");
                if (role) {   // plain store for k_post (read after kernel end)
                    u16* d2 = Hp + (size_t)(t * 64 + b) * 1024 + bkl * 8;
                    *(u32x4*)d2 = pv;
                }
            }
            if (t == 127) {
                c_out[(size_t)b * 1024 + gcol] = c;
                h_out[(size_t)b * 1024 + gcol] = h;
            }
        }
        __syncthreads();   // (2) zbuf consumed + vmcnt(0) drain: h stores visible

        // ---- publish arrival (slot per block, 64 B apart) -- plain store
        if (tid == 0)
            __hip_atomic_store(&ctr[bk * 16], (unsigned)(t + 1), __ATOMIC_RELAXED,
                               __HIP_MEMORY_SCOPE_AGENT);
    }
}

// ---------------- launcher ----------------
extern "C" void kernel_launch(void* const* d_in, const int* in_sizes, int n_in,
                              void* d_out, int out_size, void* d_ws, size_t ws_size,
                              hipStream_t stream) {
    const float* x      = (const float*)d_in[0];
    const float* c0     = (const float*)d_in[1];
    const float* h0     = (const float*)d_in[2];
    const float* W_pre  = (const float*)d_in[3];
    const float* b_pre  = (const float*)d_in[4];
    const float* ln_s   = (const float*)d_in[5];
    const float* ln_b   = (const float*)d_in[6];
    const float* Wi0    = (const float*)d_in[7];
    const float* Wh0    = (const float*)d_in[8];
    const float* b0     = (const float*)d_in[9];
    const float* Wi1    = (const float*)d_in[10];
    const float* Wh1    = (const float*)d_in[11];
    const float* b1     = (const float*)d_in[12];
    const float* W_post = (const float*)d_in[13];
    const float* b_post = (const float*)d_in[14];
    const float* W_out  = (const float*)d_in[15];
    const float* b_out  = (const float*)d_in[16];
    float* out = (float*)d_out;

    char* ws = (char*)d_ws;
    size_t off = 0;
    auto alloc = [&](size_t bytes) {
        void* p = ws + off;
        off += (bytes + 255) & ~(size_t)255;
        return p;
    };
    u16* WTpre  = (u16*)alloc((size_t)1024 * 512 * 2);
    u16* WTi0   = (u16*)alloc((size_t)4096 * 1024 * 2);
    u16* WTh0   = (u16*)alloc((size_t)4096 * 1024 * 2);
    u16* WTi1   = (u16*)alloc((size_t)4096 * 1024 * 2);
    u16* WTh1   = (u16*)alloc((size_t)4096 * 1024 * 2);
    u16* WTpost = (u16*)alloc((size_t)1024 * 1024 * 2);
    u16* WTout  = (u16*)alloc((size_t)32 * 1024 * 2);
    u16* Xb     = (u16*)alloc((size_t)8192 * 512 * 2);
    u16* preS   = (u16*)alloc((size_t)128 * 65536 * 2);   // preact, scan layout
    u16* hs0    = (u16*)alloc((size_t)129 * 65536 * 2);
    u16* hs1    = (u16*)alloc((size_t)129 * 65536 * 2);
    unsigned* ctr = (unsigned*)alloc(32768);
    u16* Hplain = (u16*)alloc((size_t)8192 * 1024 * 2);

    // prep: ctr zero + x/h0 conversions + all weight transposes
    k_prep<<<PREP_BLOCKS, 256, 0, stream>>>(
        x, Xb, h0, hs0, hs1, ctr,
        W_pre, WTpre, Wi0, WTi0, Wh0, WTh0, Wi1, WTi1, Wh1, WTh1,
        W_post, WTpost, W_out, WTout);

    // pre: Dense + LN + relu -> preS (fused, row-block local)
    k_pre<<<512, 512, 0, stream>>>(Xb, WTpre, b_pre, ln_s, ln_b, preS, 512);

    // fused symmetric 2-layer pipelined scan
    {
        const u16* WiT0_ = WTi0; const u16* WhT0_ = WTh0;
        const u16* WiT1_ = WTi1; const u16* WhT1_ = WTh1;
        const u16* preS_ = preS; const float* b0_ = b0; const float* b1_ = b1;
        const float* c0_ = c0; u16* hs0_ = hs0; u16* hs1_ = hs1;
        u16* Hp_ = Hplain; float* out_ = out; unsigned* ctr_ = ctr;
        void* args[] = {&WiT0_, &WhT0_, &WiT1_, &WhT1_, &preS_, &b0_, &b1_,
                        &c0_, &hs0_, &hs1_, &Hp_, &out_, &ctr_};
        hipLaunchCooperativeKernel((void*)k_lstm_fused, dim3(FBLOCKS), dim3(512),
                                   args, 0, stream);
    }

    // post: Dense + relu + logits (fused, activations stay in LDS)
    k_post<<<512, 512, 0, stream>>>(Hplain, WTpost, b_post, WTout, b_out, out, 1024);
}